// Round 1
// baseline (1731.173 us; speedup 1.0000x reference)
//
#include <hip/hip_runtime.h>

typedef unsigned short u16;
typedef unsigned int u32;
typedef short bf16x8 __attribute__((ext_vector_type(8)));
typedef float f32x4 __attribute__((ext_vector_type(4)));

__device__ __forceinline__ float bf2f(u16 u) {
  u32 x = ((u32)u) << 16;
  float f;
  __builtin_memcpy(&f, &x, 4);
  return f;
}
__device__ __forceinline__ u16 f2bf(float f) {
  u32 x;
  __builtin_memcpy(&x, &f, 4);
  u32 r = x + 0x7FFFu + ((x >> 16) & 1u);
  return (u16)(r >> 16);
}
// async global->LDS, 16B per lane. LDS side must be base + lane*16 contiguous.
__device__ __forceinline__ void glds16(const u16* g, u16* l) {
  __builtin_amdgcn_global_load_lds((const __attribute__((address_space(1))) u32*)g,
                                   (__attribute__((address_space(3))) u32*)l, 16, 0, 0);
}

// ---------------- geometry constants ----------------
// levels: W {256,128,64,32,16} H {160,80,40,20,10}; padded (W+2)x(H+2) NHWC bf16
// padded pixel bases: {0, 41796, 52456, 55228, 55976}, total 56192 px * 256ch

// ---------------- weight conversion / reorder ----------------
// tower layout per conv: [chunk(8)][tap(9)][o(256)][cw(32)] bf16  (589824 elems)
// heads: cls 96 rows (80 cls + 1 ctr + pad), reg 16 (4 + pad), msk 48 (36 + pad)
__global__ void convert_weights(const float* __restrict__ cw, const float* __restrict__ rw,
                                const float* __restrict__ mw, const float* __restrict__ pc,
                                const float* __restrict__ pr, const float* __restrict__ pm,
                                const float* __restrict__ pt, u16* __restrict__ dst) {
  int e = blockIdx.x * 256 + threadIdx.x;
  if (e >= 7446528) return;
  float v = 0.f;
  if (e < 7077888) {
    int conv = e / 589824, r = e % 589824;
    int chunk = r / 73728; r %= 73728;
    int tap = r / 8192; r %= 8192;
    int o = r >> 5, c = chunk * 32 + (r & 31);
    const float* s = (conv < 4) ? cw : (conv < 8) ? rw : mw;
    int si = conv & 3;
    v = s[((si * 256 + o) * 256 + c) * 9 + tap];
  } else {
    int e2 = e - 7077888;
    if (e2 < 221184) {  // cls head, MT=96
      int r = e2 % 27648;
      int tap = r / 3072; r %= 3072;
      int o = r >> 5, c = (e2 / 27648) * 32 + (r & 31);
      if (o < 80) v = pc[(o * 256 + c) * 9 + tap];
      else if (o == 80) v = pt[c * 9 + tap];
    } else if (e2 < 258048) {  // reg head, MT=16
      int e3 = e2 - 221184;
      int r = e3 % 4608;
      int tap = r / 512; r %= 512;
      int o = r >> 5, c = (e3 / 4608) * 32 + (r & 31);
      if (o < 4) v = pr[(o * 256 + c) * 9 + tap];
    } else {  // msk head, MT=48
      int e3 = e2 - 258048;
      int r = e3 % 13824;
      int tap = r / 1536; r %= 1536;
      int o = r >> 5, c = (e3 / 13824) * 32 + (r & 31);
      if (o < 36) v = pm[(o * 256 + c) * 9 + tap];
    }
  }
  dst[e] = f2bf(v);
}

// ---------------- feat NCHW fp32 -> padded NHWC bf16 ----------------
__global__ void feat_to_nhwc(const float* __restrict__ f0, const float* __restrict__ f1,
                             const float* __restrict__ f2, const float* __restrict__ f3,
                             const float* __restrict__ f4, u16* __restrict__ dst) {
  __shared__ float lds[64 * 65];
  int bx = blockIdx.x;
  int tile = bx >> 2, c0 = (bx & 3) * 64;
  int tl, sh, pxb, npx;
  const float* src;
  if (tile < 640)      { tl = tile;       sh = 8; pxb = 0;     npx = 40960; src = f0; }
  else if (tile < 800) { tl = tile - 640; sh = 7; pxb = 41796; npx = 10240; src = f1; }
  else if (tile < 840) { tl = tile - 800; sh = 6; pxb = 52456; npx = 2560;  src = f2; }
  else if (tile < 850) { tl = tile - 840; sh = 5; pxb = 55228; npx = 640;   src = f3; }
  else                 { tl = tile - 850; sh = 4; pxb = 55976; npx = 160;   src = f4; }
  int W = 1 << sh, Wp = W + 2;
  int px0 = tl * 64;
  int t = threadIdx.x;
  {
    int cc = (t >> 6) * 16, px = t & 63;
    bool ok = (px0 + px) < npx;
#pragma unroll
    for (int j = 0; j < 16; ++j) {
      float v = ok ? src[(c0 + cc + j) * npx + px0 + px] : 0.f;
      lds[(cc + j) * 65 + px] = v;
    }
  }
  __syncthreads();
  {
    int px = t >> 2, cL = (t & 3) * 16;
    int pxi = px0 + px;
    if (pxi < npx) {
      int y = pxi >> sh, x = pxi & (W - 1);
      u32 w[8];
#pragma unroll
      for (int j = 0; j < 8; ++j) {
        u16 a = f2bf(lds[(cL + 2 * j) * 65 + px]);
        u16 b = f2bf(lds[(cL + 2 * j + 1) * 65 + px]);
        w[j] = (u32)a | ((u32)b << 16);
      }
      long adr = (long)(pxb + (y + 1) * Wp + (x + 1)) * 256 + c0 + cL;
      uint4 v0 = {w[0], w[1], w[2], w[3]}, v1 = {w[4], w[5], w[6], w[7]};
      *(uint4*)(dst + adr) = v0;
      *(uint4*)(dst + adr + 8) = v1;
    }
  }
}

// ---------------- tower conv: 256->256 3x3, bf16 MFMA implicit GEMM ----------------
// block: 128 outch x 128 px (8 rows x 16 cols window); 4 waves, each 64x64 (4x4 frags)
__global__ __launch_bounds__(256, 2) void conv_tower(const u16* __restrict__ Xn,
                                                     const u16* __restrict__ Wt,
                                                     u16* __restrict__ Yraw,
                                                     float* __restrict__ stats) {
  __shared__ u16 Alds[4096];  // weights [128o][32c]
  __shared__ u16 Blds[4096];  // acts    [128px][32c]
  __shared__ float sred[32];
  int bx = blockIdx.x;
  int tile = bx >> 1, mo = bx & 1;
  int tloc, W, H, SX, pxb, lvl;
  if (tile < 320)      { lvl = 0; tloc = tile;       W = 256; H = 160; SX = 4; pxb = 0; }
  else if (tile < 400) { lvl = 1; tloc = tile - 320; W = 128; H = 80;  SX = 3; pxb = 41796; }
  else if (tile < 420) { lvl = 2; tloc = tile - 400; W = 64;  H = 40;  SX = 2; pxb = 52456; }
  else if (tile < 426) { lvl = 3; tloc = tile - 420; W = 32;  H = 20;  SX = 1; pxb = 55228; }
  else                 { lvl = 4; tloc = tile - 426; W = 16;  H = 10;  SX = 0; pxb = 55976; }
  int Wp = W + 2;
  int ty = tloc >> SX, txi = tloc & ((1 << SX) - 1);
  int y0 = ty * 8, x0 = txi * 16;
  int t = threadIdx.x, lane = t & 63, wave = t >> 6;
  int wm = wave >> 1, wn = wave & 1;
  int quad = lane >> 4, col = lane & 15;
  bool edge = (y0 + 9 > H + 1);
  int rr = t >> 6, cc4 = (t >> 2) & 15, cw8 = (t & 3) * 8;
  const u16* Xrow = Xn + (long)(pxb + (y0 + rr) * Wp + (x0 + cc4)) * 256 + cw8;
  const u16* Wb = Wt + mo * 4096 + t * 8;
  int aoff = (wm * 64 + col) * 32 + quad * 8;
  int boff = (wn * 64 + col) * 32 + quad * 8;
  f32x4 acc[4][4] = {};
  for (int ch = 0; ch < 8; ++ch) {
#pragma unroll
    for (int tap = 0; tap < 9; ++tap) {
      int dy = tap / 3, dx = tap - dy * 3;
      const u16* wsrc = Wb + (ch * 9 + tap) * 8192;
      glds16(wsrc, Alds + t * 8);
      glds16(wsrc + 2048, Alds + t * 8 + 2048);
      const u16* xsrc = Xrow + ch * 32 + (dy * Wp + dx) * 256;
      if (!edge) {
        glds16(xsrc, Blds + t * 8);
        glds16(xsrc + Wp * 1024, Blds + t * 8 + 2048);
      } else {
#pragma unroll
        for (int j = 0; j < 2; ++j) {
          int yp = y0 + rr + j * 4 + dy;
          uint4 v = {0, 0, 0, 0};
          if (yp <= H + 1) v = *(const uint4*)(xsrc + j * Wp * 1024);
          *(uint4*)(Blds + t * 8 + j * 2048) = v;
        }
      }
      __syncthreads();
      bf16x8 a[4];
#pragma unroll
      for (int mi = 0; mi < 4; ++mi) a[mi] = *(const bf16x8*)(Alds + aoff + mi * 512);
#pragma unroll
      for (int ni = 0; ni < 4; ++ni) {
        bf16x8 b = *(const bf16x8*)(Blds + boff + ni * 512);
#pragma unroll
        for (int mi = 0; mi < 4; ++mi)
          acc[mi][ni] = __builtin_amdgcn_mfma_f32_16x16x32_bf16(a[mi], b, acc[mi][ni], 0, 0, 0);
      }
      __syncthreads();
    }
  }
  // epilogue: store raw bf16 NHWC + group stats
  if (t < 32) sred[t] = 0.f;
  __syncthreads();
  long pebase = (long)(pxb + (y0 + 1) * Wp + (x0 + col + 1)) * 256;
#pragma unroll
  for (int ni = 0; ni < 4; ++ni) {
    int row = wn * 4 + ni;
    if (y0 + row < H) {
#pragma unroll
      for (int mi = 0; mi < 4; ++mi) {
        f32x4 v = acc[mi][ni];
        int o = mo * 128 + wm * 64 + mi * 16 + quad * 4;
        ushort4 pk;
        pk.x = f2bf(v[0]); pk.y = f2bf(v[1]); pk.z = f2bf(v[2]); pk.w = f2bf(v[3]);
        *(ushort4*)(Yraw + pebase + (long)row * Wp * 256 + o) = pk;
      }
    }
  }
#pragma unroll
  for (int mi = 0; mi < 4; ++mi) {
    float s1 = 0.f, s2 = 0.f;
#pragma unroll
    for (int ni = 0; ni < 4; ++ni) {
      if (y0 + wn * 4 + ni < H) {
        f32x4 v = acc[mi][ni];
#pragma unroll
        for (int r2 = 0; r2 < 4; ++r2) { float f = v[r2]; s1 += f; s2 += f * f; }
      }
    }
#pragma unroll
    for (int m = 1; m < 16; m <<= 1) { s1 += __shfl_xor(s1, m); s2 += __shfl_xor(s2, m); }
    if (col == 0) {
      int g = (wm * 64 + mi * 16 + quad * 4) >> 3;
      atomicAdd(&sred[g * 2], s1);
      atomicAdd(&sred[g * 2 + 1], s2);
    }
  }
  __syncthreads();
  if (t < 32) atomicAdd(&stats[(lvl * 32 + mo * 16 + (t >> 1)) * 2 + (t & 1)], sred[t]);
}

// ---------------- GN + ReLU elementwise (raw -> norm) ----------------
__global__ void gn_relu(const u16* __restrict__ raw, u16* __restrict__ outb,
                        const float* __restrict__ stats, const float* __restrict__ gamma,
                        const float* __restrict__ beta) {
  int i = blockIdx.x * 256 + threadIdx.x;  // 54560*32 threads, 8 ch each
  int px = i >> 5, cg = i & 31, c0 = cg << 3;
  int lvl, sh, pxb, rem;
  float cnt;
  if (px < 40960)      { lvl = 0; rem = px;         sh = 8; pxb = 0;     cnt = 327680.f; }
  else if (px < 51200) { lvl = 1; rem = px - 40960; sh = 7; pxb = 41796; cnt = 81920.f; }
  else if (px < 53760) { lvl = 2; rem = px - 51200; sh = 6; pxb = 52456; cnt = 20480.f; }
  else if (px < 54400) { lvl = 3; rem = px - 53760; sh = 5; pxb = 55228; cnt = 5120.f; }
  else                 { lvl = 4; rem = px - 54400; sh = 4; pxb = 55976; cnt = 1280.f; }
  int W = 1 << sh;
  int y = rem >> sh, x = rem & (W - 1);
  long adr = (long)(pxb + (y + 1) * (W + 2) + (x + 1)) * 256 + c0;
  uint4 rv = *(const uint4*)(raw + adr);
  float s1 = stats[(lvl * 32 + cg) * 2], s2 = stats[(lvl * 32 + cg) * 2 + 1];
  float mean = s1 / cnt;
  float var = s2 / cnt - mean * mean;
  float inv = rsqrtf(fmaxf(var, 0.f) + 1e-5f);
  u32 w[4] = {rv.x, rv.y, rv.z, rv.w};
  u32 ow[4];
#pragma unroll
  for (int j = 0; j < 4; ++j) {
    float v0 = bf2f((u16)(w[j] & 0xffff));
    float v1 = bf2f((u16)(w[j] >> 16));
    int c = c0 + 2 * j;
    v0 = fmaxf((v0 - mean) * inv * gamma[c] + beta[c], 0.f);
    v1 = fmaxf((v1 - mean) * inv * gamma[c + 1] + beta[c + 1], 0.f);
    ow[j] = (u32)f2bf(v0) | ((u32)f2bf(v1) << 16);
  }
  uint4 sv = {ow[0], ow[1], ow[2], ow[3]};
  *(uint4*)(outb + adr) = sv;
}

// ---------------- head conv: MT outputs, fused bias/scale/exp, fp32 NCHW out ----------------
// HT: 0 = cls(80)+ctr(1), 1 = reg(4, exp*scale_bbox), 2 = msk(36, exp*scale_mask)
template <int MT, int HT>
__global__ __launch_bounds__(256, 2) void conv_head(const u16* __restrict__ Xn,
                                                    const u16* __restrict__ Wh,
                                                    float* __restrict__ out,
                                                    const float* __restrict__ bias0,
                                                    const float* __restrict__ bias1,
                                                    const float* __restrict__ scales) {
  constexpr int MI = MT / 16;
  __shared__ u16 Alds[MT * 32];
  __shared__ u16 Blds[64 * 32];
  int bx = blockIdx.x;
  int lvl, tloc, W, H, SX, pxb, npx, obm, obc = 0;
  if (bx < 640) {
    lvl = 0; tloc = bx; W = 256; H = 160; SX = 4; pxb = 0; npx = 40960;
    obm = (HT == 0) ? 0 : (HT == 1) ? 4364800 : 4637600; obc = 4583040;
  } else if (bx < 800) {
    lvl = 1; tloc = bx - 640; W = 128; H = 80; SX = 3; pxb = 41796; npx = 10240;
    obm = (HT == 0) ? 3276800 : (HT == 1) ? 4528640 : 6112160; obc = 4624000;
  } else if (bx < 840) {
    lvl = 2; tloc = bx - 800; W = 64; H = 40; SX = 2; pxb = 52456; npx = 2560;
    obm = (HT == 0) ? 4096000 : (HT == 1) ? 4569600 : 6480800; obc = 4634240;
  } else if (bx < 850) {
    lvl = 3; tloc = bx - 840; W = 32; H = 20; SX = 1; pxb = 55228; npx = 640;
    obm = (HT == 0) ? 4300800 : (HT == 1) ? 4579840 : 6572960; obc = 4636800;
  } else {
    lvl = 4; tloc = bx - 850; W = 16; H = 10; SX = 0; pxb = 55976; npx = 160;
    obm = (HT == 0) ? 4352000 : (HT == 1) ? 4582400 : 6596000; obc = 4637440;
  }
  int Wp = W + 2;
  int ty = tloc >> SX, txi = tloc & ((1 << SX) - 1);
  int y0 = ty * 4, x0 = txi * 16;
  int t = threadIdx.x, lane = t & 63, wave = t >> 6;
  int quad = lane >> 4, col = lane & 15;
  bool edge = (y0 + 5 > H + 1);
  int rr = t >> 6, cc4 = (t >> 2) & 15, cw8 = (t & 3) * 8;
  const u16* Xrow = Xn + (long)(pxb + (y0 + rr) * Wp + (x0 + cc4)) * 256 + cw8;
  int aoff = col * 32 + quad * 8;
  int boff = (wave * 16 + col) * 32 + quad * 8;
  f32x4 acc[MI] = {};
  for (int ch = 0; ch < 8; ++ch) {
#pragma unroll
    for (int tap = 0; tap < 9; ++tap) {
      int dy = tap / 3, dx = tap - dy * 3;
      const u16* ws = Wh + (ch * 9 + tap) * (MT * 32);
      int ta = t * 8;
      if (ta < MT * 32) glds16(ws + ta, Alds + ta);
      if (MT * 32 > 2048) {
        int tb = ta + 2048;
        if (tb < MT * 32) glds16(ws + tb, Alds + tb);
      }
      const u16* xsrc = Xrow + ch * 32 + (dy * Wp + dx) * 256;
      if (!edge) {
        glds16(xsrc, Blds + t * 8);
      } else {
        int yp = y0 + rr + dy;
        uint4 v = {0, 0, 0, 0};
        if (yp <= H + 1) v = *(const uint4*)xsrc;
        *(uint4*)(Blds + t * 8) = v;
      }
      __syncthreads();
      bf16x8 b = *(const bf16x8*)(Blds + boff);
#pragma unroll
      for (int mi = 0; mi < MI; ++mi) {
        bf16x8 a = *(const bf16x8*)(Alds + aoff + mi * 512);
        acc[mi] = __builtin_amdgcn_mfma_f32_16x16x32_bf16(a, b, acc[mi], 0, 0, 0);
      }
      __syncthreads();
    }
  }
  int y = y0 + wave;
  if (y < H) {
    float sc = (HT == 0) ? 0.f : scales[lvl];
    int x = x0 + col;
#pragma unroll
    for (int mi = 0; mi < MI; ++mi) {
#pragma unroll
      for (int r2 = 0; r2 < 4; ++r2) {
        int o = mi * 16 + quad * 4 + r2;
        float v = acc[mi][r2];
        if (HT == 0) {
          if (o < 80) out[obm + o * npx + y * W + x] = v + bias0[o];
          else if (o == 80) out[obc + y * W + x] = v + bias1[0];
        } else if (HT == 1) {
          if (o < 4) out[obm + o * npx + y * W + x] = expf((v + bias0[o]) * sc);
        } else {
          if (o < 36) out[obm + o * npx + y * W + x] = expf((v + bias0[o]) * sc);
        }
      }
    }
  }
}

extern "C" void kernel_launch(void* const* d_in, const int* in_sizes, int n_in,
                              void* d_out, int out_size, void* d_ws, size_t ws_size,
                              hipStream_t stream) {
  const float* feat0 = (const float*)d_in[0];
  const float* feat1 = (const float*)d_in[1];
  const float* feat2 = (const float*)d_in[2];
  const float* feat3 = (const float*)d_in[3];
  const float* feat4 = (const float*)d_in[4];
  const float* cw = (const float*)d_in[5];
  const float* rw = (const float*)d_in[8];
  const float* mw = (const float*)d_in[11];
  const float* gmas[3] = {(const float*)d_in[6], (const float*)d_in[9], (const float*)d_in[12]};
  const float* btas[3] = {(const float*)d_in[7], (const float*)d_in[10], (const float*)d_in[13]};
  const float* pcw = (const float*)d_in[14];
  const float* pcb = (const float*)d_in[15];
  const float* prw = (const float*)d_in[16];
  const float* prb = (const float*)d_in[17];
  const float* pmw = (const float*)d_in[18];
  const float* pmb = (const float*)d_in[19];
  const float* ptw = (const float*)d_in[20];
  const float* ptb = (const float*)d_in[21];
  const float* sb = (const float*)d_in[22];
  const float* sm = (const float*)d_in[23];
  float* out = (float*)d_out;

  char* base = (char*)d_ws;
  u16* wts = (u16*)base;                           // 7,446,528 bf16 = 14,893,056 B
  u16* bufA = (u16*)(base + 14893056);             // raw acts, padded NHWC, 28,770,304 B
  u16* bufB = (u16*)(base + 43663360);             // norm acts, padded NHWC, 28,770,304 B
  float* stats = (float*)(base + 72433664);        // 5 lvl * 32 grp * 2 = 1280 B

  // zero halos (ws is re-poisoned before every call)
  hipMemsetAsync(bufA, 0, 28770304, stream);
  hipMemsetAsync(bufB, 0, 28770304, stream);
  convert_weights<<<29088, 256, 0, stream>>>(cw, rw, mw, pcw, prw, pmw, ptw, wts);

  for (int tw = 0; tw < 3; ++tw) {
    feat_to_nhwc<<<3412, 256, 0, stream>>>(feat0, feat1, feat2, feat3, feat4, bufB);
    for (int s = 0; s < 4; ++s) {
      hipMemsetAsync(stats, 0, 1280, stream);
      conv_tower<<<856, 256, 0, stream>>>(bufB, wts + (tw * 4 + s) * 589824, bufA, stats);
      gn_relu<<<6820, 256, 0, stream>>>(bufA, bufB, stats, gmas[tw] + s * 256, btas[tw] + s * 256);
    }
    if (tw == 0)
      conv_head<96, 0><<<853, 256, 0, stream>>>(bufB, wts + 7077888, out, pcb, ptb, sb);
    else if (tw == 1)
      conv_head<16, 1><<<853, 256, 0, stream>>>(bufB, wts + 7299072, out, prb, nullptr, sb);
    else
      conv_head<48, 2><<<853, 256, 0, stream>>>(bufB, wts + 7335936, out, pmb, nullptr, sm);
  }
}

// Round 2
// 1616.910 us; speedup vs baseline: 1.0707x; 1.0707x over previous
//
#include <hip/hip_runtime.h>

typedef unsigned short u16;
typedef unsigned int u32;
typedef short bf16x8 __attribute__((ext_vector_type(8)));
typedef float f32x4 __attribute__((ext_vector_type(4)));

__device__ __forceinline__ float bf2f(u16 u) {
  u32 x = ((u32)u) << 16;
  float f;
  __builtin_memcpy(&f, &x, 4);
  return f;
}
__device__ __forceinline__ u16 f2bf(float f) {
  u32 x;
  __builtin_memcpy(&x, &f, 4);
  u32 r = x + 0x7FFFu + ((x >> 16) & 1u);
  return (u16)(r >> 16);
}
// async global->LDS, 16B per lane. LDS dest must be wave-uniform base + lane*16.
__device__ __forceinline__ void glds16(const u16* g, u16* l) {
  __builtin_amdgcn_global_load_lds((const __attribute__((address_space(1))) u32*)g,
                                   (__attribute__((address_space(3))) u32*)l, 16, 0, 0);
}

// ---------------- geometry ----------------
// levels: W {256,128,64,32,16} H {160,80,40,20,10}; padded (W+2)x(H+2) NHWC bf16
// padded pixel bases {0, 41796, 52456, 55228, 55976}; total 56192 px
// per-tower activation stride = 56192*256 = 14,385,152 u16 elements

// ---------------- weight conversion ----------------
// tower layout per conv: [chunk(8)][tap(9)][mo(2)][g(4)][o(128)][c8(8)]   (589824 elems)
// head layout per (chunk,tap): [g(4)][o(MT)][c8(8)]  (MT: cls 96, reg 16, msk 48)
__global__ void convert_weights(const float* __restrict__ cw, const float* __restrict__ rw,
                                const float* __restrict__ mw, const float* __restrict__ pc,
                                const float* __restrict__ pr, const float* __restrict__ pm,
                                const float* __restrict__ pt, u16* __restrict__ dst) {
  int e = blockIdx.x * 256 + threadIdx.x;
  if (e >= 7446528) return;
  float v = 0.f;
  if (e < 7077888) {
    int conv = e / 589824, r = e % 589824;
    int chunk = r / 73728; r %= 73728;
    int tap = r / 8192; r %= 8192;
    int mo = r >> 12;
    int g = (r >> 10) & 3;
    int o = mo * 128 + ((r >> 3) & 127);
    int c = chunk * 32 + g * 8 + (r & 7);
    const float* s = (conv < 4) ? cw : (conv < 8) ? rw : mw;
    int si = conv & 3;
    v = s[((si * 256 + o) * 256 + c) * 9 + tap];
  } else {
    int e2 = e - 7077888;
    if (e2 < 221184) {  // cls head, MT=96 (80 cls + 1 ctr + pad)
      int chunk = e2 / 27648, r = e2 % 27648;
      int tap = r / 3072, r2 = r % 3072;
      int g = r2 / 768;
      int o = (r2 - g * 768) >> 3;
      int c = chunk * 32 + g * 8 + (r2 & 7);
      if (o < 80) v = pc[(o * 256 + c) * 9 + tap];
      else if (o == 80) v = pt[c * 9 + tap];
    } else if (e2 < 258048) {  // reg head, MT=16
      int e3 = e2 - 221184;
      int chunk = e3 / 4608, r = e3 % 4608;
      int tap = r / 512, r2 = r % 512;
      int g = r2 >> 7;
      int o = (r2 >> 3) & 15;
      int c = chunk * 32 + g * 8 + (r2 & 7);
      if (o < 4) v = pr[(o * 256 + c) * 9 + tap];
    } else {  // msk head, MT=48
      int e3 = e2 - 258048;
      int chunk = e3 / 13824, r = e3 % 13824;
      int tap = r / 1536, r2 = r % 1536;
      int g = r2 / 384;
      int o = (r2 - g * 384) >> 3;
      int c = chunk * 32 + g * 8 + (r2 & 7);
      if (o < 36) v = pm[(o * 256 + c) * 9 + tap];
    }
  }
  dst[e] = f2bf(v);
}

// ---------------- feat NCHW fp32 -> padded NHWC bf16 (replicated nrep towers) ------
__global__ void feat_to_nhwc(const float* __restrict__ f0, const float* __restrict__ f1,
                             const float* __restrict__ f2, const float* __restrict__ f3,
                             const float* __restrict__ f4, u16* __restrict__ dst,
                             long tstride, int nrep) {
  __shared__ float lds[64 * 65];
  int bx = blockIdx.x;
  int tile = bx >> 2, c0 = (bx & 3) * 64;
  int tl, sh, pxb, npx;
  const float* src;
  if (tile < 640)      { tl = tile;       sh = 8; pxb = 0;     npx = 40960; src = f0; }
  else if (tile < 800) { tl = tile - 640; sh = 7; pxb = 41796; npx = 10240; src = f1; }
  else if (tile < 840) { tl = tile - 800; sh = 6; pxb = 52456; npx = 2560;  src = f2; }
  else if (tile < 850) { tl = tile - 840; sh = 5; pxb = 55228; npx = 640;   src = f3; }
  else                 { tl = tile - 850; sh = 4; pxb = 55976; npx = 160;   src = f4; }
  int W = 1 << sh, Wp = W + 2;
  int px0 = tl * 64;
  int t = threadIdx.x;
  {
    int cc = (t >> 6) * 16, px = t & 63;
    bool ok = (px0 + px) < npx;
#pragma unroll
    for (int j = 0; j < 16; ++j) {
      float v = ok ? src[(c0 + cc + j) * npx + px0 + px] : 0.f;
      lds[(cc + j) * 65 + px] = v;
    }
  }
  __syncthreads();
  {
    int px = t >> 2, cL = (t & 3) * 16;
    int pxi = px0 + px;
    if (pxi < npx) {
      int y = pxi >> sh, x = pxi & (W - 1);
      u32 w[8];
#pragma unroll
      for (int j = 0; j < 8; ++j) {
        u16 a = f2bf(lds[(cL + 2 * j) * 65 + px]);
        u16 b = f2bf(lds[(cL + 2 * j + 1) * 65 + px]);
        w[j] = (u32)a | ((u32)b << 16);
      }
      long adr = (long)(pxb + (y + 1) * Wp + (x + 1)) * 256 + c0 + cL;
      uint4 v0 = {w[0], w[1], w[2], w[3]}, v1 = {w[4], w[5], w[6], w[7]};
      for (int r = 0; r < nrep; ++r) {
        *(uint4*)(dst + r * tstride + adr) = v0;
        *(uint4*)(dst + r * tstride + adr + 8) = v1;
      }
    }
  }
}

// ---------------- tower conv: 256->256 3x3, bf16 MFMA implicit GEMM ----------------
// grid = ntow*856 blocks; tower = bx/856. 128 outch x 128 px tile, 4 waves, 4x4 frags.
// LDS layouts (conflict-free): A [g(4)][o(128)][8], B [g(4)][p(128)][8]
__global__ __launch_bounds__(256, 2) void conv_tower(const u16* __restrict__ Xn, long in_ts,
                                                     const u16* __restrict__ Wt, long wt_ts,
                                                     u16* __restrict__ Yraw, long out_ts,
                                                     float* __restrict__ stats, int st_ts) {
  __shared__ u16 Alds[4096];
  __shared__ u16 Blds[4096];
  __shared__ float sred[32];
  int bx = blockIdx.x;
  int tw = bx / 856, r856 = bx - tw * 856;
  Xn += tw * in_ts; Wt += tw * wt_ts; Yraw += tw * out_ts; stats += tw * st_ts;
  int tile = r856 >> 1, mo = r856 & 1;
  int tloc, W, H, SX, pxb, lvl;
  if (tile < 320)      { lvl = 0; tloc = tile;       W = 256; H = 160; SX = 4; pxb = 0; }
  else if (tile < 400) { lvl = 1; tloc = tile - 320; W = 128; H = 80;  SX = 3; pxb = 41796; }
  else if (tile < 420) { lvl = 2; tloc = tile - 400; W = 64;  H = 40;  SX = 2; pxb = 52456; }
  else if (tile < 426) { lvl = 3; tloc = tile - 420; W = 32;  H = 20;  SX = 1; pxb = 55228; }
  else                 { lvl = 4; tloc = tile - 426; W = 16;  H = 10;  SX = 0; pxb = 55976; }
  int Wp = W + 2;
  int ty = tloc >> SX, txi = tloc & ((1 << SX) - 1);
  int y0 = ty * 8, x0 = txi * 16;
  int t = threadIdx.x, lane = t & 63, wave = t >> 6;
  int wm = wave >> 1, wn = wave & 1;
  int quad = lane >> 4, col = lane & 15;
  bool edge = (y0 + 9 > H + 1);
  // staging map: thread t -> pixel p=(t&127) [row p>>4, col p&15], ch-group gg=t>>7
  int rr = (t & 127) >> 4, cc = t & 15, gg = t >> 7;
  const u16* Xrow = Xn + (long)(pxb + (y0 + rr) * Wp + (x0 + cc)) * 256 + gg * 8;
  const u16* Wb = Wt + mo * 4096 + t * 8;
  int aoff = quad * 1024 + (wm * 64 + col) * 8;
  int boff = quad * 1024 + (wn * 64 + col) * 8;
  f32x4 acc[4][4] = {};
  for (int ch = 0; ch < 8; ++ch) {
#pragma unroll
    for (int tap = 0; tap < 9; ++tap) {
      int dy = tap / 3, dx = tap - dy * 3;
      const u16* wsrc = Wb + (ch * 9 + tap) * 8192;
      glds16(wsrc, Alds + t * 8);
      glds16(wsrc + 2048, Alds + t * 8 + 2048);
      const u16* xsrc = Xrow + ch * 32 + (dy * Wp + dx) * 256;
      if (!edge) {
        glds16(xsrc, Blds + t * 8);         // ch-groups gg, gg+? -> g in {0,1}
        glds16(xsrc + 16, Blds + t * 8 + 2048);  // g in {2,3} (+16 channels)
      } else {
        int yp = y0 + rr + dy;
        uint4 v0 = {0, 0, 0, 0}, v1 = {0, 0, 0, 0};
        if (yp <= H + 1) { v0 = *(const uint4*)xsrc; v1 = *(const uint4*)(xsrc + 16); }
        *(uint4*)(Blds + t * 8) = v0;
        *(uint4*)(Blds + t * 8 + 2048) = v1;
      }
      __syncthreads();
      bf16x8 a[4];
#pragma unroll
      for (int mi = 0; mi < 4; ++mi) a[mi] = *(const bf16x8*)(Alds + aoff + mi * 128);
#pragma unroll
      for (int ni = 0; ni < 4; ++ni) {
        bf16x8 b = *(const bf16x8*)(Blds + boff + ni * 128);
#pragma unroll
        for (int mi = 0; mi < 4; ++mi)
          acc[mi][ni] = __builtin_amdgcn_mfma_f32_16x16x32_bf16(a[mi], b, acc[mi][ni], 0, 0, 0);
      }
      __syncthreads();
    }
  }
  // epilogue: store raw bf16 NHWC + group stats
  if (t < 32) sred[t] = 0.f;
  __syncthreads();
  long pebase = (long)(pxb + (y0 + 1) * Wp + (x0 + col + 1)) * 256;
#pragma unroll
  for (int ni = 0; ni < 4; ++ni) {
    int row = wn * 4 + ni;
    if (y0 + row < H) {
#pragma unroll
      for (int mi = 0; mi < 4; ++mi) {
        f32x4 v = acc[mi][ni];
        int o = mo * 128 + wm * 64 + mi * 16 + quad * 4;
        ushort4 pk;
        pk.x = f2bf(v[0]); pk.y = f2bf(v[1]); pk.z = f2bf(v[2]); pk.w = f2bf(v[3]);
        *(ushort4*)(Yraw + pebase + (long)row * Wp * 256 + o) = pk;
      }
    }
  }
#pragma unroll
  for (int mi = 0; mi < 4; ++mi) {
    float s1 = 0.f, s2 = 0.f;
#pragma unroll
    for (int ni = 0; ni < 4; ++ni) {
      if (y0 + wn * 4 + ni < H) {
        f32x4 v = acc[mi][ni];
#pragma unroll
        for (int r2 = 0; r2 < 4; ++r2) { float f = v[r2]; s1 += f; s2 += f * f; }
      }
    }
#pragma unroll
    for (int m = 1; m < 16; m <<= 1) { s1 += __shfl_xor(s1, m); s2 += __shfl_xor(s2, m); }
    if (col == 0) {
      int g = (wm * 64 + mi * 16 + quad * 4) >> 3;
      atomicAdd(&sred[g * 2], s1);
      atomicAdd(&sred[g * 2 + 1], s2);
    }
  }
  __syncthreads();
  if (t < 32) atomicAdd(&stats[(lvl * 32 + mo * 16 + (t >> 1)) * 2 + (t & 1)], sred[t]);
}

// ---------------- GN + ReLU elementwise, in-place ----------------
__global__ void gn_relu(u16* __restrict__ buf, long tstride,
                        const float* __restrict__ stats, int st_ts,
                        const float* __restrict__ g0, const float* __restrict__ g1,
                        const float* __restrict__ g2, const float* __restrict__ b0,
                        const float* __restrict__ b1, const float* __restrict__ b2) {
  int i = blockIdx.x * 256 + threadIdx.x;
  int tw = i / 1745920;            // 54560*32 per tower
  int j = i - tw * 1745920;
  buf += tw * tstride;
  stats += tw * st_ts;
  const float* gamma = (tw == 0) ? g0 : (tw == 1) ? g1 : g2;
  const float* beta = (tw == 0) ? b0 : (tw == 1) ? b1 : b2;
  int px = j >> 5, cg = j & 31, c0 = cg << 3;
  int lvl, sh, pxb, rem;
  float cnt;
  if (px < 40960)      { lvl = 0; rem = px;         sh = 8; pxb = 0;     cnt = 327680.f; }
  else if (px < 51200) { lvl = 1; rem = px - 40960; sh = 7; pxb = 41796; cnt = 81920.f; }
  else if (px < 53760) { lvl = 2; rem = px - 51200; sh = 6; pxb = 52456; cnt = 20480.f; }
  else if (px < 54400) { lvl = 3; rem = px - 53760; sh = 5; pxb = 55228; cnt = 5120.f; }
  else                 { lvl = 4; rem = px - 54400; sh = 4; pxb = 55976; cnt = 1280.f; }
  int W = 1 << sh;
  int y = rem >> sh, x = rem & (W - 1);
  long adr = (long)(pxb + (y + 1) * (W + 2) + (x + 1)) * 256 + c0;
  uint4 rv = *(const uint4*)(buf + adr);
  float s1 = stats[(lvl * 32 + cg) * 2], s2 = stats[(lvl * 32 + cg) * 2 + 1];
  float mean = s1 / cnt;
  float var = s2 / cnt - mean * mean;
  float inv = rsqrtf(fmaxf(var, 0.f) + 1e-5f);
  u32 w[4] = {rv.x, rv.y, rv.z, rv.w};
  u32 ow[4];
#pragma unroll
  for (int jj = 0; jj < 4; ++jj) {
    float v0 = bf2f((u16)(w[jj] & 0xffff));
    float v1 = bf2f((u16)(w[jj] >> 16));
    int c = c0 + 2 * jj;
    v0 = fmaxf((v0 - mean) * inv * gamma[c] + beta[c], 0.f);
    v1 = fmaxf((v1 - mean) * inv * gamma[c + 1] + beta[c + 1], 0.f);
    ow[jj] = (u32)f2bf(v0) | ((u32)f2bf(v1) << 16);
  }
  uint4 sv = {ow[0], ow[1], ow[2], ow[3]};
  *(uint4*)(buf + adr) = sv;
}

// ---------------- head conv: MT outputs, fused bias/scale/exp, fp32 NCHW out -------
// HT: 0 = cls(80)+ctr(1), 1 = reg(4, exp*scale), 2 = msk(36, exp*scale)
// LDS layouts: A [g(4)][o(MT)][8], B [g(4)][p(64)][8]
template <int MT, int HT>
__global__ __launch_bounds__(256, 2) void conv_head(const u16* __restrict__ Xn,
                                                    const u16* __restrict__ Wh,
                                                    float* __restrict__ out,
                                                    const float* __restrict__ bias0,
                                                    const float* __restrict__ bias1,
                                                    const float* __restrict__ scales) {
  constexpr int MI = MT / 16;
  __shared__ u16 Alds[MT * 32];
  __shared__ u16 Blds[64 * 32];
  int bx = blockIdx.x;
  int lvl, tloc, W, H, SX, pxb, npx, obm, obc = 0;
  if (bx < 640) {
    lvl = 0; tloc = bx; W = 256; H = 160; SX = 4; pxb = 0; npx = 40960;
    obm = (HT == 0) ? 0 : (HT == 1) ? 4364800 : 4637600; obc = 4583040;
  } else if (bx < 800) {
    lvl = 1; tloc = bx - 640; W = 128; H = 80; SX = 3; pxb = 41796; npx = 10240;
    obm = (HT == 0) ? 3276800 : (HT == 1) ? 4528640 : 6112160; obc = 4624000;
  } else if (bx < 840) {
    lvl = 2; tloc = bx - 800; W = 64; H = 40; SX = 2; pxb = 52456; npx = 2560;
    obm = (HT == 0) ? 4096000 : (HT == 1) ? 4569600 : 6480800; obc = 4634240;
  } else if (bx < 850) {
    lvl = 3; tloc = bx - 840; W = 32; H = 20; SX = 1; pxb = 55228; npx = 640;
    obm = (HT == 0) ? 4300800 : (HT == 1) ? 4579840 : 6572960; obc = 4636800;
  } else {
    lvl = 4; tloc = bx - 850; W = 16; H = 10; SX = 0; pxb = 55976; npx = 160;
    obm = (HT == 0) ? 4352000 : (HT == 1) ? 4582400 : 6596000; obc = 4637440;
  }
  int Wp = W + 2;
  int ty = tloc >> SX, txi = tloc & ((1 << SX) - 1);
  int y0 = ty * 4, x0 = txi * 16;
  int t = threadIdx.x, lane = t & 63, wave = t >> 6;
  int quad = lane >> 4, col = lane & 15;
  bool edge = (y0 + 5 > H + 1);
  int rr = (t & 63) >> 4, cc = t & 15, gg = t >> 6;
  const u16* Xrow = Xn + (long)(pxb + (y0 + rr) * Wp + (x0 + cc)) * 256 + gg * 8;
  int aoff = quad * (MT * 8) + col * 8;
  int boff = quad * 512 + (wave * 16 + col) * 8;
  f32x4 acc[MI] = {};
  for (int ch = 0; ch < 8; ++ch) {
#pragma unroll
    for (int tap = 0; tap < 9; ++tap) {
      int dy = tap / 3, dx = tap - dy * 3;
      const u16* ws = Wh + (ch * 9 + tap) * (MT * 32);
      int ta = t * 8;
      if (ta < MT * 32) glds16(ws + ta, Alds + ta);
      if (MT * 32 > 2048) {
        int tb = ta + 2048;
        if (tb < MT * 32) glds16(ws + tb, Alds + tb);
      }
      const u16* xsrc = Xrow + ch * 32 + (dy * Wp + dx) * 256;
      if (!edge) {
        glds16(xsrc, Blds + t * 8);
      } else {
        int yp = y0 + rr + dy;
        uint4 v = {0, 0, 0, 0};
        if (yp <= H + 1) v = *(const uint4*)xsrc;
        *(uint4*)(Blds + t * 8) = v;
      }
      __syncthreads();
      bf16x8 b = *(const bf16x8*)(Blds + boff);
#pragma unroll
      for (int mi = 0; mi < MI; ++mi) {
        bf16x8 a = *(const bf16x8*)(Alds + aoff + mi * 128);
        acc[mi] = __builtin_amdgcn_mfma_f32_16x16x32_bf16(a, b, acc[mi], 0, 0, 0);
      }
      __syncthreads();
    }
  }
  int y = y0 + wave;
  if (y < H) {
    float sc = (HT == 0) ? 0.f : scales[lvl];
    int x = x0 + col;
#pragma unroll
    for (int mi = 0; mi < MI; ++mi) {
#pragma unroll
      for (int r2 = 0; r2 < 4; ++r2) {
        int o = mi * 16 + quad * 4 + r2;
        float v = acc[mi][r2];
        if (HT == 0) {
          if (o < 80) out[obm + o * npx + y * W + x] = v + bias0[o];
          else if (o == 80) out[obc + y * W + x] = v + bias1[0];
        } else if (HT == 1) {
          if (o < 4) out[obm + o * npx + y * W + x] = expf((v + bias0[o]) * sc);
        } else {
          if (o < 36) out[obm + o * npx + y * W + x] = expf((v + bias0[o]) * sc);
        }
      }
    }
  }
}

extern "C" void kernel_launch(void* const* d_in, const int* in_sizes, int n_in,
                              void* d_out, int out_size, void* d_ws, size_t ws_size,
                              hipStream_t stream) {
  const float* feat0 = (const float*)d_in[0];
  const float* feat1 = (const float*)d_in[1];
  const float* feat2 = (const float*)d_in[2];
  const float* feat3 = (const float*)d_in[3];
  const float* feat4 = (const float*)d_in[4];
  const float* cw = (const float*)d_in[5];
  const float* rw = (const float*)d_in[8];
  const float* mw = (const float*)d_in[11];
  const float* gmas[3] = {(const float*)d_in[6], (const float*)d_in[9], (const float*)d_in[12]};
  const float* btas[3] = {(const float*)d_in[7], (const float*)d_in[10], (const float*)d_in[13]};
  const float* pcw = (const float*)d_in[14];
  const float* pcb = (const float*)d_in[15];
  const float* prw = (const float*)d_in[16];
  const float* prb = (const float*)d_in[17];
  const float* pmw = (const float*)d_in[18];
  const float* pmb = (const float*)d_in[19];
  const float* ptw = (const float*)d_in[20];
  const float* ptb = (const float*)d_in[21];
  const float* sb = (const float*)d_in[22];
  const float* sm = (const float*)d_in[23];
  float* out = (float*)d_out;

  const long ACT = 14385152;         // u16 elems per tower activation buffer
  const long ACTB = 28770304;        // bytes
  char* base = (char*)d_ws;
  u16* wts = (u16*)base;             // 14,893,056 B

  size_t need_fused = 14893056 + 2 * 3 * (size_t)ACTB + 3840;  // 187,518,720 B

  convert_weights<<<29088, 256, 0, stream>>>(cw, rw, mw, pcw, prw, pmw, ptw, wts);

  if (ws_size >= need_fused) {
    // -------- fused path: all 3 towers in one dispatch per layer --------
    u16* X = (u16*)(base + 14893056);               // 3 towers
    u16* Y = (u16*)(base + 14893056 + 3 * ACTB);    // 3 towers
    float* stats = (float*)(base + 14893056 + 6 * ACTB);
    hipMemsetAsync(X, 0, 3 * ACTB, stream);
    hipMemsetAsync(Y, 0, 3 * ACTB, stream);
    feat_to_nhwc<<<3412, 256, 0, stream>>>(feat0, feat1, feat2, feat3, feat4, X, ACT, 3);
    for (int s = 0; s < 4; ++s) {
      u16* in = (s & 1) ? Y : X;
      u16* ot = (s & 1) ? X : Y;
      hipMemsetAsync(stats, 0, 3840, stream);
      conv_tower<<<2568, 256, 0, stream>>>(in, ACT, wts + s * 589824, 4 * 589824, ot, ACT,
                                           stats, 320);
      gn_relu<<<20460, 256, 0, stream>>>(ot, ACT, stats, 320,
                                         gmas[0] + s * 256, gmas[1] + s * 256, gmas[2] + s * 256,
                                         btas[0] + s * 256, btas[1] + s * 256, btas[2] + s * 256);
    }
    // after s=3 the normalized activations are in X
    conv_head<96, 0><<<853, 256, 0, stream>>>(X, wts + 7077888, out, pcb, ptb, sb);
    conv_head<16, 1><<<853, 256, 0, stream>>>(X + ACT, wts + 7299072, out, prb, nullptr, sb);
    conv_head<48, 2><<<853, 256, 0, stream>>>(X + 2 * ACT, wts + 7335936, out, pmb, nullptr, sm);
  } else {
    // -------- fallback: sequential towers (fits in 72.5 MB) --------
    u16* bufA = (u16*)(base + 14893056);
    u16* bufB = (u16*)(base + 14893056 + ACTB);
    float* stats = (float*)(base + 14893056 + 2 * ACTB);
    hipMemsetAsync(bufA, 0, ACTB, stream);
    hipMemsetAsync(bufB, 0, ACTB, stream);
    for (int tw = 0; tw < 3; ++tw) {
      feat_to_nhwc<<<3412, 256, 0, stream>>>(feat0, feat1, feat2, feat3, feat4, bufB, 0, 1);
      for (int s = 0; s < 4; ++s) {
        u16* in = (s & 1) ? bufA : bufB;
        u16* ot = (s & 1) ? bufB : bufA;
        hipMemsetAsync(stats, 0, 1280, stream);
        conv_tower<<<856, 256, 0, stream>>>(in, 0, wts + (tw * 4 + s) * 589824, 0, ot, 0,
                                            stats, 0);
        gn_relu<<<6820, 256, 0, stream>>>(ot, 0, stats, 0,
                                          gmas[tw] + s * 256, gmas[tw] + s * 256, gmas[tw] + s * 256,
                                          btas[tw] + s * 256, btas[tw] + s * 256, btas[tw] + s * 256);
      }
      if (tw == 0)
        conv_head<96, 0><<<853, 256, 0, stream>>>(bufB, wts + 7077888, out, pcb, ptb, sb);
      else if (tw == 1)
        conv_head<16, 1><<<853, 256, 0, stream>>>(bufB, wts + 7299072, out, prb, nullptr, sb);
      else
        conv_head<48, 2><<<853, 256, 0, stream>>>(bufB, wts + 7335936, out, pmb, nullptr, sm);
    }
  }
}